// Round 1
// baseline (275.268 us; speedup 1.0000x reference)
//
#include <hip/hip_runtime.h>
#include <math.h>

#define BATCH 32768
#define NE 9
#define RANK 50
#define DIM 450            // NE * RANK
#define REL_DIM 900        // 2 * DIM

__device__ __forceinline__ float softplusf(float x) {
    return (x > 20.f) ? x : log1pf(expf(x));
}
__device__ __forceinline__ float phif(float z) {
    return 0.5f * (1.f + erff(z * 0.70710678118654752f));
}

// One 64-lane wave per sample.
__global__ __launch_bounds__(64) void k_main(
    const int* __restrict__ queries, const int* __restrict__ these_queries,
    const float* __restrict__ entity, const float* __restrict__ rel,
    const float* __restrict__ rel_diag, const float* __restrict__ bh,
    const float* __restrict__ bt, const float* __restrict__ c_param,
    const float* __restrict__ cnn_w, const float* __restrict__ cnn_b,
    const float* __restrict__ h2e_w, const float* __restrict__ h2e_b,
    const float* __restrict__ cnnn_w, const float* __restrict__ cnnn_b,
    const float* __restrict__ h2en_w, const float* __restrict__ h2en_b,
    const float* __restrict__ noise,
    float* __restrict__ y_out, float* __restrict__ ws_gate, float* __restrict__ ws_prob)
{
    const int b = blockIdx.x;
    const int l = threadIdx.x;

    __shared__ float xs[1350];           // head (450) ++ rel_q (900)
    __shared__ float feat[128], featn[128];
    __shared__ float clean_s[NE], std_s[NE], noisy_s[NE];
    __shared__ float cont[64];
    __shared__ int   sidx[2];
    __shared__ float sg[2];
    __shared__ float sthr[2];            // [0] = thr_in (3rd), [1] = thr_out (2nd)

    const int q0 = queries[b * 3 + 0];
    const int q1 = queries[b * 3 + 1];
    const int t2 = these_queries[b * 3 + 2];

    const float* headp = entity + (size_t)q0 * DIM;
    const float* relp  = rel + (size_t)q1 * REL_DIM;

    for (int i = l; i < DIM; i += 64)      xs[i] = headp[i];
    for (int i = l; i < REL_DIM; i += 64)  xs[DIM + i] = relp[i];
    __syncthreads();

    // Two 5x5 stride-3 VALID convs over (27,50); 128 outputs each; 2 per lane.
    float w0[25], w1[25];
#pragma unroll
    for (int k = 0; k < 25; ++k) { w0[k] = cnn_w[k]; w1[k] = cnnn_w[k]; }
    const float cb0 = cnn_b[0], cb1 = cnnn_b[0];
#pragma unroll
    for (int rep = 0; rep < 2; ++rep) {
        int o = l + rep * 64;
        int oh = o >> 4, ow = o & 15;
        const float* base = xs + (oh * 3) * RANK + ow * 3;
        float a0 = cb0, a1 = cb1;
#pragma unroll
        for (int i = 0; i < 5; ++i)
#pragma unroll
            for (int j = 0; j < 5; ++j) {
                float v = base[i * RANK + j];
                a0 = fmaf(v, w0[i * 5 + j], a0);
                a1 = fmaf(v, w1[i * 5 + j], a1);
            }
        feat[o] = a0; featn[o] = a1;
    }
    __syncthreads();

    // clean[e] (lanes 0..8) and std[e] (lanes 9..17): 128-length dots.
    if (l < 18) {
        int e = (l < 9) ? l : (l - 9);
        const float* wrow = (l < 9) ? (h2e_w + e * 128) : (h2en_w + e * 128);
        const float* fv   = (l < 9) ? feat : featn;
        float acc = 0.f;
#pragma unroll 8
        for (int o = 0; o < 128; ++o) acc = fmaf(fv[o], wrow[o], acc);
        if (l < 9) clean_s[e] = acc + h2e_b[e];
        else       std_s[e]   = softplusf(acc + h2en_b[e]) + 0.01f;
    }
    __syncthreads();
    if (l < NE) noisy_s[l] = clean_s[l] + noise[(size_t)b * NE + l] * std_s[l];
    __syncthreads();

    // top-3 of 9 noisy values (ties -> lower index, matching lax.top_k)
    if (l == 0) {
        int i0 = -1, i1 = -1;
        float v0 = -__builtin_huge_valf(), v1 = v0, v2 = v0;
#pragma unroll
        for (int e = 0; e < NE; ++e) {
            float v = noisy_s[e];
            if (v > v0)      { v2 = v1; v1 = v0; i1 = i0; v0 = v; i0 = e; }
            else if (v > v1) { v2 = v1; v1 = v; i1 = e; }
            else if (v > v2) { v2 = v; }
        }
        float e0 = expf(v0 - v0), e1 = expf(v1 - v0);
        float inv = 1.f / (e0 + e1);
        sidx[0] = i0; sidx[1] = i1;
        sg[0] = e0 * inv; sg[1] = e1 * inv;
        sthr[0] = v2; sthr[1] = v1;
    }
    __syncthreads();

    // prob (load) and gates (importance) per expert -> workspace columns
    if (l < NE) {
        float thr_in = sthr[0], thr_out = sthr[1];
        float n = noisy_s[l];
        float thr = (n > thr_in) ? thr_in : thr_out;
        ws_prob[(size_t)l * BATCH + b] = phif((clean_s[l] - thr) / std_s[l]);
        float g = (l == sidx[0]) ? sg[0] : ((l == sidx[1]) ? sg[1] : 0.f);
        ws_gate[(size_t)l * BATCH + b] = g;
    }

    // Givens + dist2 only for the 2 selected experts (mask = gates > 0)
    const float* rdp  = rel_diag + (size_t)q1 * DIM;
    const float* rhsp = entity + (size_t)t2 * DIM;
    float contrib = 0.f;
    if (l < 50) {
        int sel = l / 25;
        int p = l - sel * 25;
        int e = sidx[sel];
        int bix = e * RANK + 2 * p;
        float r0 = rdp[bix], r1 = rdp[bix + 1];
        float x0 = xs[bix],  x1 = xs[bix + 1];
        float nrm = fmaxf(sqrtf(r0 * r0 + r1 * r1), 1e-15f);
        float c0 = r0 / nrm, c1 = r1 / nrm;
        float o0 = c0 * x0 - c1 * x1;
        float o1 = c1 * x0 + c0 * x1;
        int rbase = DIM + e * (2 * RANK) + 2 * p;
        float lhs0 = o0 + xs[rbase];
        float lhs1 = o1 + xs[rbase + 1];
        float d0 = lhs0 - rhsp[bix];
        float d1 = lhs1 - rhsp[bix + 1];
        contrib = d0 * d0 + d1 * d1;
    }
    cont[l] = contrib;
    __syncthreads();

    if (l == 0) {
        float d2a = 0.f, d2b = 0.f;
#pragma unroll
        for (int i = 0; i < 25; ++i) { d2a += cont[i]; d2b += cont[25 + i]; }
        float c = softplusf(c_param[q1]);
        float base = bh[q0] + bt[t2];
        float s = expf(base - c * d2a) + expf(base - c * d2b);
        y_out[b] = logf((s == 0.f) ? 2.2204460492503131e-16f : s);
    }
}

// One block per column j of 18 (9 gate cols -> importance, 9 prob cols -> load)
__global__ __launch_bounds__(256) void k_reduce(const float* __restrict__ ws,
                                                float* __restrict__ sums)
{
    int j = blockIdx.x;
    const float* col = ws + (size_t)j * BATCH;
    __shared__ float red[256];
    float acc = 0.f;
    for (int i = threadIdx.x; i < BATCH; i += 256) acc += col[i];
    red[threadIdx.x] = acc;
    __syncthreads();
    for (int s = 128; s > 0; s >>= 1) {
        if (threadIdx.x < s) red[threadIdx.x] += red[threadIdx.x + s];
        __syncthreads();
    }
    if (threadIdx.x == 0) sums[j] = red[0];
}

__global__ void k_loss(const float* __restrict__ sums, float* __restrict__ out)
{
    if (threadIdx.x == 0 && blockIdx.x == 0) {
        float loss = 0.f;
#pragma unroll
        for (int part = 0; part < 2; ++part) {
            const float* v = sums + part * NE;   // part0: importance (gates), part1: load (prob)
            float mean = 0.f;
            for (int i = 0; i < NE; ++i) mean += v[i];
            mean /= 9.f;
            float var = 0.f;
            for (int i = 0; i < NE; ++i) { float d = v[i] - mean; var += d * d; }
            var /= 8.f;                           // ddof=1
            loss += var / (mean * mean + 1e-10f);
        }
        out[BATCH] = 0.01f * loss;
    }
}

extern "C" void kernel_launch(void* const* d_in, const int* in_sizes, int n_in,
                              void* d_out, int out_size, void* d_ws, size_t ws_size,
                              hipStream_t stream)
{
    const int*   queries = (const int*)d_in[0];
    const int*   these   = (const int*)d_in[1];
    const float* entity  = (const float*)d_in[2];
    const float* rel     = (const float*)d_in[3];
    const float* rel_dg  = (const float*)d_in[4];
    const float* bh      = (const float*)d_in[5];
    const float* bt      = (const float*)d_in[6];
    const float* c_par   = (const float*)d_in[7];
    const float* cnn_w   = (const float*)d_in[8];
    const float* cnn_b   = (const float*)d_in[9];
    const float* h2e_w   = (const float*)d_in[10];
    const float* h2e_b   = (const float*)d_in[11];
    const float* cnnn_w  = (const float*)d_in[12];
    const float* cnnn_b  = (const float*)d_in[13];
    const float* h2en_w  = (const float*)d_in[14];
    const float* h2en_b  = (const float*)d_in[15];
    const float* noise   = (const float*)d_in[16];

    float* y  = (float*)d_out;
    float* ws = (float*)d_ws;
    float* ws_gate = ws;                              // 9*BATCH
    float* ws_prob = ws + (size_t)9 * BATCH;          // 9*BATCH
    float* sums    = ws + (size_t)18 * BATCH;         // 18

    k_main<<<BATCH, 64, 0, stream>>>(queries, these, entity, rel, rel_dg, bh, bt, c_par,
                                     cnn_w, cnn_b, h2e_w, h2e_b, cnnn_w, cnnn_b,
                                     h2en_w, h2en_b, noise, y, ws_gate, ws_prob);
    k_reduce<<<18, 256, 0, stream>>>(ws, sums);
    k_loss<<<1, 64, 0, stream>>>(sums, y);
}